// Round 9
// baseline (69.058 us; speedup 1.0000x reference)
//
#include <hip/hip_runtime.h>

#define NN 2048
#define NH 4
#define COLS 256   // NH*F_OUT

typedef __attribute__((ext_vector_type(8))) short short8;
typedef __attribute__((ext_vector_type(4))) float f32x4;
typedef __attribute__((ext_vector_type(4))) int i32x4;
typedef __attribute__((ext_vector_type(4))) unsigned u32x4;

__device__ __forceinline__ unsigned cvtpk(float lo, float hi) {
  unsigned r;
  asm("v_cvt_pk_bf16_f32 %0, %1, %2" : "=v"(r) : "v"(lo), "v"(hi));
  return r;
}
__device__ __forceinline__ unsigned pack16(i32x4 a, i32x4 b, i32x4 c, i32x4 d) {
  unsigned m = 0;
  #pragma unroll
  for (int e = 0; e < 4; ++e) {
    m |= (a[e] != 0 ? 1u : 0u) << e;
    m |= (b[e] != 0 ? 1u : 0u) << (e + 4);
    m |= (c[e] != 0 ? 1u : 0u) << (e + 8);
    m |= (d[e] != 0 ? 1u : 0u) << (e + 12);
  }
  return m;
}

// ---------------------------------------------------------------------------
// Kernel 1: h = X @ W (f32 accum). grid 1024 x 256, 8 rows/block.
//   hB : bf16, MFMA B-fragment-contiguous:
//        chunk = ((bh*64 + jc)*4 + t)*64 + (grp*16 + fl), 8 ushorts/chunk
//        holds h[n = jc*32+grp*8+e][f = t*16+fl].
//   s_src/s_dst : f32 [bh][n], PRE-SCALED by log2(e).
// ---------------------------------------------------------------------------
__global__ __launch_bounds__(256) void k1_prep(
    const float* __restrict__ nf, const float* __restrict__ W,
    const float* __restrict__ att, ushort* __restrict__ hB,
    float* __restrict__ s_src, float* __restrict__ s_dst)
{
  const int tid = threadIdx.x;
  const int head = tid >> 6, lane = tid & 63;
  const int bid = blockIdx.x;
  const int m0 = bid * 8;

  float w[64];
  #pragma unroll
  for (int f = 0; f < 64; ++f) w[f] = W[f * COLS + tid];   // coalesced

  const float LOG2E = 1.4426950408889634f;
  const float asrc = att[head * 128 + lane] * LOG2E;
  const float adst = att[head * 128 + 64 + lane] * LOG2E;

  __shared__ float xs[512];
  xs[tid]       = nf[m0 * 64 + tid];
  xs[tid + 256] = nf[m0 * 64 + 256 + tid];
  __syncthreads();

  float hv[8];
  #pragma unroll
  for (int rr = 0; rr < 8; ++rr) {
    float acc = 0.f;
    #pragma unroll
    for (int f = 0; f < 64; ++f) acc = fmaf(xs[rr * 64 + f], w[f], acc);
    hv[rr] = acc;
    float vs = acc * asrc, vd = acc * adst;
    #pragma unroll
    for (int off = 32; off > 0; off >>= 1) {
      vs += __shfl_xor(vs, off);
      vd += __shfl_xor(vd, off);
    }
    if (lane == 0) {
      const int m = m0 + rr;
      const int b = m >> 11, n = m & (NN - 1);
      s_src[(b * NH + head) * NN + n] = vs;
      s_dst[(b * NH + head) * NN + n] = vd;
    }
  }

  const int b   = m0 >> 11;
  const int n0  = m0 & (NN - 1);
  const int jc  = n0 >> 5;
  const int grp = (n0 >> 3) & 3;
  const int t   = (tid >> 4) & 3, fl = tid & 15;
  uint4 vv;
  vv.x = cvtpk(hv[0], hv[1]);
  vv.y = cvtpk(hv[2], hv[3]);
  vv.z = cvtpk(hv[4], hv[5]);
  vv.w = cvtpk(hv[6], hv[7]);
  const size_t chunk =
      (((size_t)(b * NH + head) * 64 + jc) * 4 + t) * 64 + (grp * 16 + fl);
  *(uint4*)(hB + chunk * 8) = vv;
}

// ---------------------------------------------------------------------------
// Kernel 2: fused mask + leakyrelu + softmax + P@H via MFMA 16x16x32 bf16.
// grid 512 x 512 thr (8 waves = head x j-half); 16 i-rows/block; 2 blocks/CU.
// adj bits staged once (4KB padded LDS) -> barrier-free main loop with
// EXPLICIT 2-DEEP REGISTER PREFETCH of sd + hB (separates load from use by
// ~2 loop bodies so L2 latency hides under VALU+MFMA).
// ---------------------------------------------------------------------------
struct Pf {
  f32x4 sd0, sd1;
  short8 hb0, hb1, hb2, hb3;
};

__device__ __forceinline__ Pf load_pf(const float* __restrict__ sdp,
                                      const ushort* __restrict__ hbW,
                                      int jc, int koff) {
  Pf c;
  const int jb = jc * 32 + koff;
  c.sd0 = *(const f32x4*)(sdp + jb);
  c.sd1 = *(const f32x4*)(sdp + jb + 4);
  const ushort* hc = hbW + jc * 2048;
  c.hb0 = *(const short8*)(hc);
  c.hb1 = *(const short8*)(hc + 512);
  c.hb2 = *(const short8*)(hc + 1024);
  c.hb3 = *(const short8*)(hc + 1536);
  return c;
}

__global__ __launch_bounds__(512) void k2_main(
    const int* __restrict__ adj, const ushort* __restrict__ hB,
    const float* __restrict__ s_src, const float* __restrict__ s_dst,
    float* __restrict__ out)
{
  const int tid = threadIdx.x;
  const int wv  = tid >> 6;
  const int h   = wv >> 1;            // head
  const int js  = wv & 1;             // j-half
  const int l   = tid & 63;
  const int L   = blockIdx.x;
  const int b    = (L & 7) >> 1;                 // XCD swizzle: 2 XCDs/batch
  const int iblk = ((L >> 3) << 1) + (L & 1);    // bijective
  const int i0   = iblk << 4;

  const int bh   = b * NH + h;
  const int r16  = l & 15;
  const int grp  = l >> 4;
  const int koff = grp << 3;

  __shared__ unsigned abits[16][65];      // 16 rows x 2048 bits, padded
  __shared__ float red[NH][5][4][64];     // 20KB epilogue, stride-1/lane

  // ---- stage adj -> bits (once). thread: row = tid>>5, seg = tid&31 (64 j)
  {
    const int srow = tid >> 5, sseg = tid & 31;
    const int* sb = adj + ((size_t)(b * NN + i0 + srow)) * NN + sseg * 64;
    unsigned m[4];
    #pragma unroll
    for (int q = 0; q < 4; ++q) {
      const i32x4 a0 = *(const i32x4*)(sb + q * 16);
      const i32x4 a1 = *(const i32x4*)(sb + q * 16 + 4);
      const i32x4 a2 = *(const i32x4*)(sb + q * 16 + 8);
      const i32x4 a3 = *(const i32x4*)(sb + q * 16 + 12);
      m[q] = pack16(a0, a1, a2, a3);
    }
    abits[srow][sseg * 2]     = m[0] | (m[1] << 16);
    abits[srow][sseg * 2 + 1] = m[2] | (m[3] << 16);
  }
  __syncthreads();

  const float ssl = s_src[bh * NN + i0 + r16];
  const float*  sdp = s_dst + bh * NN;
  const ushort* hbW = hB + (size_t)bh * 131072 + l * 8;

  const short8 ones = {(short)0x3F80, (short)0x3F80, (short)0x3F80, (short)0x3F80,
                       (short)0x3F80, (short)0x3F80, (short)0x3F80, (short)0x3F80};

  f32x4 acc[4];
  #pragma unroll
  for (int q = 0; q < 4; ++q) acc[q] = (f32x4){0.f, 0.f, 0.f, 0.f};
  f32x4 acd = (f32x4){0.f, 0.f, 0.f, 0.f};

  const int jc0 = js * 32, jcE = jc0 + 31;
  Pf cur = load_pf(sdp, hbW, jc0, koff);
  Pf nx1 = load_pf(sdp, hbW, jc0 + 1, koff);

  // ---- main loop: 32 jc iterations, barrier-free, 2-deep prefetch
  #pragma unroll 1
  for (int jc = jc0; jc <= jcE; ++jc) {
    const int jp = (jc + 2 <= jcE) ? jc + 2 : jcE;
    Pf nx2 = load_pf(sdp, hbW, jp, koff);

    const unsigned msk = abits[r16][jc] >> koff;

    float pl[8];
    #pragma unroll
    for (int e = 0; e < 8; ++e) {
      const float sdv = (e < 4) ? cur.sd0[e] : cur.sd1[e - 4];
      float x = ssl + sdv;                 // pre-scaled by log2(e)
      x = fmaxf(x, 0.2f * x);
      const float p = __builtin_amdgcn_exp2f(x);
      pl[e] = ((msk >> e) & 1u) ? p : 0.f;
    }
    u32x4 pa;
    #pragma unroll
    for (int e2 = 0; e2 < 4; ++e2) pa[e2] = cvtpk(pl[2 * e2], pl[2 * e2 + 1]);
    union { u32x4 u; short8 s; } ca; ca.u = pa;
    const short8 pal = ca.s;

    acc[0] = __builtin_amdgcn_mfma_f32_16x16x32_bf16(pal, cur.hb0, acc[0], 0, 0, 0);
    acc[1] = __builtin_amdgcn_mfma_f32_16x16x32_bf16(pal, cur.hb1, acc[1], 0, 0, 0);
    acc[2] = __builtin_amdgcn_mfma_f32_16x16x32_bf16(pal, cur.hb2, acc[2], 0, 0, 0);
    acc[3] = __builtin_amdgcn_mfma_f32_16x16x32_bf16(pal, cur.hb3, acc[3], 0, 0, 0);
    acd    = __builtin_amdgcn_mfma_f32_16x16x32_bf16(pal, ones,    acd,    0, 0, 0);

    cur = nx1;
    nx1 = nx2;
  }

  // ---- 2-way js reduction: one barrier
  if (js) {
    #pragma unroll
    for (int t = 0; t < 4; ++t)
      #pragma unroll
      for (int r = 0; r < 4; ++r) red[h][t][r][l] = acc[t][r];
    #pragma unroll
    for (int r = 0; r < 4; ++r) red[h][4][r][l] = acd[r];
  }
  __syncthreads();

  if (!js) {
    #pragma unroll
    for (int t = 0; t < 4; ++t)
      #pragma unroll
      for (int r = 0; r < 4; ++r) acc[t][r] += red[h][t][r][l];
    #pragma unroll
    for (int r = 0; r < 4; ++r) acd[r] += red[h][4][r][l];

    float rl[4];
    #pragma unroll
    for (int r = 0; r < 4; ++r) rl[r] = 1.0f / acd[r];
    #pragma unroll
    for (int t = 0; t < 4; ++t) {
      #pragma unroll
      for (int r = 0; r < 4; ++r) {
        const int i = i0 + grp * 4 + r;
        const size_t oidx = ((size_t)(b * NN + i) * COLS) + h * 64 + t * 16 + r16;
        out[oidx] = acc[t][r] * rl[r];
      }
    }
  }
}

// ---------------------------------------------------------------------------
extern "C" void kernel_launch(void* const* d_in, const int* in_sizes, int n_in,
                              void* d_out, int out_size, void* d_ws, size_t ws_size,
                              hipStream_t stream) {
  const float* nf  = (const float*)d_in[0];
  const int*   adj = (const int*)d_in[1];
  const float* W   = (const float*)d_in[2];
  const float* att = (const float*)d_in[3];

  ushort* hB    = (ushort*)d_ws;                                  // 4 MB
  float*  s_src = (float*)((char*)d_ws + (size_t)16 * 64 * NN * 2);
  float*  s_dst = s_src + 16 * NN;

  hipLaunchKernelGGL(k1_prep, dim3(1024), dim3(256), 0, stream,
                     nf, W, att, hB, s_src, s_dst);
  hipLaunchKernelGGL(k2_main, dim3(512), dim3(512), 0, stream,
                     adj, hB, s_src, s_dst, (float*)d_out);
}

// Round 10
// 68.610 us; speedup vs baseline: 1.0065x; 1.0065x over previous
//
#include <hip/hip_runtime.h>

#define NN 2048
#define NH 4
#define COLS 256   // NH*F_OUT

typedef __attribute__((ext_vector_type(8))) short short8;
typedef __attribute__((ext_vector_type(4))) float f32x4;
typedef __attribute__((ext_vector_type(4))) int i32x4;
typedef __attribute__((ext_vector_type(4))) unsigned u32x4;

__device__ __forceinline__ unsigned cvtpk(float lo, float hi) {
  unsigned r;
  asm("v_cvt_pk_bf16_f32 %0, %1, %2" : "=v"(r) : "v"(lo), "v"(hi));
  return r;
}
__device__ __forceinline__ unsigned pack16(i32x4 a, i32x4 b, i32x4 c, i32x4 d) {
  unsigned m = 0;
  #pragma unroll
  for (int e = 0; e < 4; ++e) {
    m |= (a[e] != 0 ? 1u : 0u) << e;
    m |= (b[e] != 0 ? 1u : 0u) << (e + 4);
    m |= (c[e] != 0 ? 1u : 0u) << (e + 8);
    m |= (d[e] != 0 ? 1u : 0u) << (e + 12);
  }
  return m;
}

// ---------------------------------------------------------------------------
// Kernel 1: h = X @ W (f32 accum). grid 1024 x 256, 8 rows/block.
//   hB : bf16, MFMA B-fragment-contiguous:
//        chunk = ((bh*64 + jc)*4 + t)*64 + (grp*16 + fl), 8 ushorts/chunk
//        holds h[n = jc*32+grp*8+e][f = t*16+fl].
//   s_src/s_dst : f32 [bh][n], PRE-SCALED by log2(e).
// ---------------------------------------------------------------------------
__global__ __launch_bounds__(256) void k1_prep(
    const float* __restrict__ nf, const float* __restrict__ W,
    const float* __restrict__ att, ushort* __restrict__ hB,
    float* __restrict__ s_src, float* __restrict__ s_dst)
{
  const int tid = threadIdx.x;
  const int head = tid >> 6, lane = tid & 63;
  const int bid = blockIdx.x;
  const int m0 = bid * 8;

  float w[64];
  #pragma unroll
  for (int f = 0; f < 64; ++f) w[f] = W[f * COLS + tid];   // coalesced

  const float LOG2E = 1.4426950408889634f;
  const float asrc = att[head * 128 + lane] * LOG2E;
  const float adst = att[head * 128 + 64 + lane] * LOG2E;

  __shared__ float xs[512];
  xs[tid]       = nf[m0 * 64 + tid];
  xs[tid + 256] = nf[m0 * 64 + 256 + tid];
  __syncthreads();

  float hv[8];
  #pragma unroll
  for (int rr = 0; rr < 8; ++rr) {
    float acc = 0.f;
    #pragma unroll
    for (int f = 0; f < 64; ++f) acc = fmaf(xs[rr * 64 + f], w[f], acc);
    hv[rr] = acc;
    float vs = acc * asrc, vd = acc * adst;
    #pragma unroll
    for (int off = 32; off > 0; off >>= 1) {
      vs += __shfl_xor(vs, off);
      vd += __shfl_xor(vd, off);
    }
    if (lane == 0) {
      const int m = m0 + rr;
      const int b = m >> 11, n = m & (NN - 1);
      s_src[(b * NH + head) * NN + n] = vs;
      s_dst[(b * NH + head) * NN + n] = vd;
    }
  }

  const int b   = m0 >> 11;
  const int n0  = m0 & (NN - 1);
  const int jc  = n0 >> 5;
  const int grp = (n0 >> 3) & 3;
  const int t   = (tid >> 4) & 3, fl = tid & 15;
  uint4 vv;
  vv.x = cvtpk(hv[0], hv[1]);
  vv.y = cvtpk(hv[2], hv[3]);
  vv.z = cvtpk(hv[4], hv[5]);
  vv.w = cvtpk(hv[6], hv[7]);
  const size_t chunk =
      (((size_t)(b * NH + head) * 64 + jc) * 4 + t) * 64 + (grp * 16 + fl);
  *(uint4*)(hB + chunk * 8) = vv;
}

// ---------------------------------------------------------------------------
// Kernel 2: fused mask + leakyrelu + softmax + P@H via MFMA 16x16x32 bf16.
// grid 512 x 512 thr (8 waves = head x j-half); 16 i-rows/block; 2 blocks/CU.
// __launch_bounds__(512, 4): min 4 waves/EU -> VGPR cap 128 (pool 512/SIMD),
// matching the actual residency (2 blk/CU x 8 waves = 4/EU). This frees the
// allocator to keep the 2-deep prefetch (3x24 VGPR) live — r7-r9 showed the
// default occupancy-targeting starves to 32-36 VGPR and serializes loads.
// ---------------------------------------------------------------------------
struct Pf {
  f32x4 sd0, sd1;
  short8 hb0, hb1, hb2, hb3;
};

__device__ __forceinline__ Pf load_pf(const float* __restrict__ sdp,
                                      const ushort* __restrict__ hbW,
                                      int jc, int koff) {
  Pf c;
  const int jb = jc * 32 + koff;
  c.sd0 = *(const f32x4*)(sdp + jb);
  c.sd1 = *(const f32x4*)(sdp + jb + 4);
  const ushort* hc = hbW + jc * 2048;
  c.hb0 = *(const short8*)(hc);
  c.hb1 = *(const short8*)(hc + 512);
  c.hb2 = *(const short8*)(hc + 1024);
  c.hb3 = *(const short8*)(hc + 1536);
  return c;
}

__global__ __launch_bounds__(512, 4) void k2_main(
    const int* __restrict__ adj, const ushort* __restrict__ hB,
    const float* __restrict__ s_src, const float* __restrict__ s_dst,
    float* __restrict__ out)
{
  const int tid = threadIdx.x;
  const int wv  = tid >> 6;
  const int h   = wv >> 1;            // head
  const int js  = wv & 1;             // j-half
  const int l   = tid & 63;
  const int L   = blockIdx.x;
  const int b    = (L & 7) >> 1;                 // XCD swizzle: 2 XCDs/batch
  const int iblk = ((L >> 3) << 1) + (L & 1);    // bijective
  const int i0   = iblk << 4;

  const int bh   = b * NH + h;
  const int r16  = l & 15;
  const int grp  = l >> 4;
  const int koff = grp << 3;

  __shared__ unsigned abits[16][65];      // 16 rows x 2048 bits, padded
  __shared__ float red[NH][5][4][64];     // 20KB epilogue, stride-1/lane

  // ---- stage adj -> bits (once). thread: row = tid>>5, seg = tid&31 (64 j)
  {
    const int srow = tid >> 5, sseg = tid & 31;
    const int* sb = adj + ((size_t)(b * NN + i0 + srow)) * NN + sseg * 64;
    unsigned m[4];
    #pragma unroll
    for (int q = 0; q < 4; ++q) {
      const i32x4 a0 = *(const i32x4*)(sb + q * 16);
      const i32x4 a1 = *(const i32x4*)(sb + q * 16 + 4);
      const i32x4 a2 = *(const i32x4*)(sb + q * 16 + 8);
      const i32x4 a3 = *(const i32x4*)(sb + q * 16 + 12);
      m[q] = pack16(a0, a1, a2, a3);
    }
    abits[srow][sseg * 2]     = m[0] | (m[1] << 16);
    abits[srow][sseg * 2 + 1] = m[2] | (m[3] << 16);
  }
  __syncthreads();

  const float ssl = s_src[bh * NN + i0 + r16];
  const float*  sdp = s_dst + bh * NN;
  const ushort* hbW = hB + (size_t)bh * 131072 + l * 8;

  const short8 ones = {(short)0x3F80, (short)0x3F80, (short)0x3F80, (short)0x3F80,
                       (short)0x3F80, (short)0x3F80, (short)0x3F80, (short)0x3F80};

  f32x4 acc[4];
  #pragma unroll
  for (int q = 0; q < 4; ++q) acc[q] = (f32x4){0.f, 0.f, 0.f, 0.f};
  f32x4 acd = (f32x4){0.f, 0.f, 0.f, 0.f};

  const int jc0 = js * 32, jcE = jc0 + 31;
  Pf cur = load_pf(sdp, hbW, jc0, koff);
  Pf nx1 = load_pf(sdp, hbW, jc0 + 1, koff);

  // ---- main loop: 32 jc iterations, barrier-free, 2-deep prefetch
  #pragma unroll 1
  for (int jc = jc0; jc <= jcE; ++jc) {
    const int jp = (jc + 2 <= jcE) ? jc + 2 : jcE;
    Pf nx2 = load_pf(sdp, hbW, jp, koff);

    const unsigned msk = abits[r16][jc] >> koff;

    float pl[8];
    #pragma unroll
    for (int e = 0; e < 8; ++e) {
      const float sdv = (e < 4) ? cur.sd0[e] : cur.sd1[e - 4];
      float x = ssl + sdv;                 // pre-scaled by log2(e)
      x = fmaxf(x, 0.2f * x);
      const float p = __builtin_amdgcn_exp2f(x);
      pl[e] = ((msk >> e) & 1u) ? p : 0.f;
    }
    u32x4 pa;
    #pragma unroll
    for (int e2 = 0; e2 < 4; ++e2) pa[e2] = cvtpk(pl[2 * e2], pl[2 * e2 + 1]);
    union { u32x4 u; short8 s; } ca; ca.u = pa;
    const short8 pal = ca.s;

    acc[0] = __builtin_amdgcn_mfma_f32_16x16x32_bf16(pal, cur.hb0, acc[0], 0, 0, 0);
    acc[1] = __builtin_amdgcn_mfma_f32_16x16x32_bf16(pal, cur.hb1, acc[1], 0, 0, 0);
    acc[2] = __builtin_amdgcn_mfma_f32_16x16x32_bf16(pal, cur.hb2, acc[2], 0, 0, 0);
    acc[3] = __builtin_amdgcn_mfma_f32_16x16x32_bf16(pal, cur.hb3, acc[3], 0, 0, 0);
    acd    = __builtin_amdgcn_mfma_f32_16x16x32_bf16(pal, ones,    acd,    0, 0, 0);

    cur = nx1;
    nx1 = nx2;
  }

  // ---- 2-way js reduction: one barrier
  if (js) {
    #pragma unroll
    for (int t = 0; t < 4; ++t)
      #pragma unroll
      for (int r = 0; r < 4; ++r) red[h][t][r][l] = acc[t][r];
    #pragma unroll
    for (int r = 0; r < 4; ++r) red[h][4][r][l] = acd[r];
  }
  __syncthreads();

  if (!js) {
    #pragma unroll
    for (int t = 0; t < 4; ++t)
      #pragma unroll
      for (int r = 0; r < 4; ++r) acc[t][r] += red[h][t][r][l];
    #pragma unroll
    for (int r = 0; r < 4; ++r) acd[r] += red[h][4][r][l];

    float rl[4];
    #pragma unroll
    for (int r = 0; r < 4; ++r) rl[r] = 1.0f / acd[r];
    #pragma unroll
    for (int t = 0; t < 4; ++t) {
      #pragma unroll
      for (int r = 0; r < 4; ++r) {
        const int i = i0 + grp * 4 + r;
        const size_t oidx = ((size_t)(b * NN + i) * COLS) + h * 64 + t * 16 + r16;
        out[oidx] = acc[t][r] * rl[r];
      }
    }
  }
}

// ---------------------------------------------------------------------------
extern "C" void kernel_launch(void* const* d_in, const int* in_sizes, int n_in,
                              void* d_out, int out_size, void* d_ws, size_t ws_size,
                              hipStream_t stream) {
  const float* nf  = (const float*)d_in[0];
  const int*   adj = (const int*)d_in[1];
  const float* W   = (const float*)d_in[2];
  const float* att = (const float*)d_in[3];

  ushort* hB    = (ushort*)d_ws;                                  // 4 MB
  float*  s_src = (float*)((char*)d_ws + (size_t)16 * 64 * NN * 2);
  float*  s_dst = s_src + 16 * NN;

  hipLaunchKernelGGL(k1_prep, dim3(1024), dim3(256), 0, stream,
                     nf, W, att, hB, s_src, s_dst);
  hipLaunchKernelGGL(k2_main, dim3(512), dim3(512), 0, stream,
                     adj, hB, s_src, s_dst, (float*)d_out);
}

// Round 11
// 57.908 us; speedup vs baseline: 1.1926x; 1.1848x over previous
//
#include <hip/hip_runtime.h>

#define NN 2048
#define NH 4
#define COLS 256   // NH*F_OUT

typedef __attribute__((ext_vector_type(8))) short short8;
typedef __attribute__((ext_vector_type(4))) float f32x4;
typedef __attribute__((ext_vector_type(4))) int i32x4;
typedef __attribute__((ext_vector_type(4))) unsigned u32x4;

__device__ __forceinline__ unsigned cvtpk(float lo, float hi) {
  unsigned r;
  asm("v_cvt_pk_bf16_f32 %0, %1, %2" : "=v"(r) : "v"(lo), "v"(hi));
  return r;
}
__device__ __forceinline__ unsigned pack16(i32x4 a, i32x4 b, i32x4 c, i32x4 d) {
  unsigned m = 0;
  #pragma unroll
  for (int e = 0; e < 4; ++e) {
    m |= (a[e] != 0 ? 1u : 0u) << e;
    m |= (b[e] != 0 ? 1u : 0u) << (e + 4);
    m |= (c[e] != 0 ? 1u : 0u) << (e + 8);
    m |= (d[e] != 0 ? 1u : 0u) << (e + 12);
  }
  return m;
}

// ---------------------------------------------------------------------------
// Kernel 1: h = X @ W (f32 accum). grid 1024 x 256, 8 rows/block.
//   hB : bf16, MFMA B-fragment-contiguous:
//        chunk = ((bh*64 + jc)*4 + t)*64 + (grp*16 + fl), 8 ushorts/chunk
//        holds h[n = jc*32+grp*8+e][f = t*16+fl].
//   s_src/s_dst : f32 [bh][n], PRE-SCALED by log2(e).
// ---------------------------------------------------------------------------
__global__ __launch_bounds__(256) void k1_prep(
    const float* __restrict__ nf, const float* __restrict__ W,
    const float* __restrict__ att, ushort* __restrict__ hB,
    float* __restrict__ s_src, float* __restrict__ s_dst)
{
  const int tid = threadIdx.x;
  const int head = tid >> 6, lane = tid & 63;
  const int bid = blockIdx.x;
  const int m0 = bid * 8;

  float w[64];
  #pragma unroll
  for (int f = 0; f < 64; ++f) w[f] = W[f * COLS + tid];   // coalesced

  const float LOG2E = 1.4426950408889634f;
  const float asrc = att[head * 128 + lane] * LOG2E;
  const float adst = att[head * 128 + 64 + lane] * LOG2E;

  __shared__ float xs[512];
  xs[tid]       = nf[m0 * 64 + tid];
  xs[tid + 256] = nf[m0 * 64 + 256 + tid];
  __syncthreads();

  float hv[8];
  #pragma unroll
  for (int rr = 0; rr < 8; ++rr) {
    float acc = 0.f;
    #pragma unroll
    for (int f = 0; f < 64; ++f) acc = fmaf(xs[rr * 64 + f], w[f], acc);
    hv[rr] = acc;
    float vs = acc * asrc, vd = acc * adst;
    #pragma unroll
    for (int off = 32; off > 0; off >>= 1) {
      vs += __shfl_xor(vs, off);
      vd += __shfl_xor(vd, off);
    }
    if (lane == 0) {
      const int m = m0 + rr;
      const int b = m >> 11, n = m & (NN - 1);
      s_src[(b * NH + head) * NN + n] = vs;
      s_dst[(b * NH + head) * NN + n] = vd;
    }
  }

  const int b   = m0 >> 11;
  const int n0  = m0 & (NN - 1);
  const int jc  = n0 >> 5;
  const int grp = (n0 >> 3) & 3;
  const int t   = (tid >> 4) & 3, fl = tid & 15;
  uint4 vv;
  vv.x = cvtpk(hv[0], hv[1]);
  vv.y = cvtpk(hv[2], hv[3]);
  vv.z = cvtpk(hv[4], hv[5]);
  vv.w = cvtpk(hv[6], hv[7]);
  const size_t chunk =
      (((size_t)(b * NH + head) * 64 + jc) * 4 + t) * 64 + (grp * 16 + fl);
  *(uint4*)(hB + chunk * 8) = vv;
}

// ---------------------------------------------------------------------------
// Kernel 2: fused mask + leakyrelu + softmax + P@H via MFMA 16x16x32 bf16.
// grid 512 x 512 thr (8 waves = head x j-half); 16 i-rows/block; 2 blocks/CU.
// amdgpu_waves_per_eu(4,4): pins the backend's occupancy TARGET to the real
// residency (4 waves/EU) -> 128-VGPR budget, so the 2-deep prefetch can live
// in registers. r10 A/B proved launch_bounds' 2nd arg (min only) cannot do
// this: backend targeted 8 waves/EU (LDS-derived), starved to 32 VGPR, and
// serialized 6 load round-trips/iter = 4200cy/iter = the 57us wall.
// ---------------------------------------------------------------------------
struct Pf {
  f32x4 sd0, sd1;
  short8 hb0, hb1, hb2, hb3;
};

__device__ __forceinline__ Pf load_pf(const float* __restrict__ sdp,
                                      const ushort* __restrict__ hbW,
                                      int jc, int koff) {
  Pf c;
  const int jb = jc * 32 + koff;
  c.sd0 = *(const f32x4*)(sdp + jb);
  c.sd1 = *(const f32x4*)(sdp + jb + 4);
  const ushort* hc = hbW + jc * 2048;
  c.hb0 = *(const short8*)(hc);
  c.hb1 = *(const short8*)(hc + 512);
  c.hb2 = *(const short8*)(hc + 1024);
  c.hb3 = *(const short8*)(hc + 1536);
  return c;
}

__global__ __launch_bounds__(512)
__attribute__((amdgpu_waves_per_eu(4, 4)))
void k2_main(
    const int* __restrict__ adj, const ushort* __restrict__ hB,
    const float* __restrict__ s_src, const float* __restrict__ s_dst,
    float* __restrict__ out)
{
  const int tid = threadIdx.x;
  const int wv  = tid >> 6;
  const int h   = wv >> 1;            // head
  const int js  = wv & 1;             // j-half
  const int l   = tid & 63;
  const int L   = blockIdx.x;
  const int b    = (L & 7) >> 1;                 // XCD swizzle: 2 XCDs/batch
  const int iblk = ((L >> 3) << 1) + (L & 1);    // bijective
  const int i0   = iblk << 4;

  const int bh   = b * NH + h;
  const int r16  = l & 15;
  const int grp  = l >> 4;
  const int koff = grp << 3;

  __shared__ unsigned abits[16][65];      // 16 rows x 2048 bits, padded
  __shared__ float red[NH][5][4][64];     // 20KB epilogue, stride-1/lane

  // ---- stage adj -> bits (once). thread: row = tid>>5, seg = tid&31 (64 j)
  {
    const int srow = tid >> 5, sseg = tid & 31;
    const int* sb = adj + ((size_t)(b * NN + i0 + srow)) * NN + sseg * 64;
    unsigned m[4];
    #pragma unroll
    for (int q = 0; q < 4; ++q) {
      const i32x4 a0 = *(const i32x4*)(sb + q * 16);
      const i32x4 a1 = *(const i32x4*)(sb + q * 16 + 4);
      const i32x4 a2 = *(const i32x4*)(sb + q * 16 + 8);
      const i32x4 a3 = *(const i32x4*)(sb + q * 16 + 12);
      m[q] = pack16(a0, a1, a2, a3);
    }
    abits[srow][sseg * 2]     = m[0] | (m[1] << 16);
    abits[srow][sseg * 2 + 1] = m[2] | (m[3] << 16);
  }
  __syncthreads();

  const float ssl = s_src[bh * NN + i0 + r16];
  const float*  sdp = s_dst + bh * NN;
  const ushort* hbW = hB + (size_t)bh * 131072 + l * 8;

  const short8 ones = {(short)0x3F80, (short)0x3F80, (short)0x3F80, (short)0x3F80,
                       (short)0x3F80, (short)0x3F80, (short)0x3F80, (short)0x3F80};

  f32x4 acc[4];
  #pragma unroll
  for (int q = 0; q < 4; ++q) acc[q] = (f32x4){0.f, 0.f, 0.f, 0.f};
  f32x4 acd = (f32x4){0.f, 0.f, 0.f, 0.f};

  const int jc0 = js * 32, jcE = jc0 + 31;
  Pf cur = load_pf(sdp, hbW, jc0, koff);
  Pf nx1 = load_pf(sdp, hbW, jc0 + 1, koff);

#define K2_BODY(JC)                                                            \
  {                                                                            \
    const unsigned msk = abits[r16][(JC)] >> koff;                             \
    float pl[8];                                                               \
    _Pragma("unroll")                                                          \
    for (int e = 0; e < 8; ++e) {                                              \
      const float sdv = (e < 4) ? cur.sd0[e] : cur.sd1[e - 4];                 \
      float x = ssl + sdv;                                                     \
      x = fmaxf(x, 0.2f * x);                                                  \
      const float p = __builtin_amdgcn_exp2f(x);                               \
      pl[e] = ((msk >> e) & 1u) ? p : 0.f;                                     \
    }                                                                          \
    u32x4 pa;                                                                  \
    _Pragma("unroll")                                                          \
    for (int e2 = 0; e2 < 4; ++e2) pa[e2] = cvtpk(pl[2 * e2], pl[2 * e2 + 1]); \
    union { u32x4 u; short8 s; } ca; ca.u = pa;                                \
    const short8 pal = ca.s;                                                   \
    acc[0] = __builtin_amdgcn_mfma_f32_16x16x32_bf16(pal, cur.hb0, acc[0], 0, 0, 0); \
    acc[1] = __builtin_amdgcn_mfma_f32_16x16x32_bf16(pal, cur.hb1, acc[1], 0, 0, 0); \
    acc[2] = __builtin_amdgcn_mfma_f32_16x16x32_bf16(pal, cur.hb2, acc[2], 0, 0, 0); \
    acc[3] = __builtin_amdgcn_mfma_f32_16x16x32_bf16(pal, cur.hb3, acc[3], 0, 0, 0); \
    acd    = __builtin_amdgcn_mfma_f32_16x16x32_bf16(pal, ones,    acd,    0, 0, 0); \
  }

  // ---- main loop: steady-state with UNCONDITIONAL jc+2 prefetch
  #pragma unroll 1
  for (int jc = jc0; jc <= jcE - 2; ++jc) {
    Pf nx2 = load_pf(sdp, hbW, jc + 2, koff);
    K2_BODY(jc);
    cur = nx1;
    nx1 = nx2;
  }
  // peeled tail (2 iters, no prefetch)
  K2_BODY(jcE - 1);
  cur = nx1;
  K2_BODY(jcE);
#undef K2_BODY

  // ---- 2-way js reduction: one barrier
  if (js) {
    #pragma unroll
    for (int t = 0; t < 4; ++t)
      #pragma unroll
      for (int r = 0; r < 4; ++r) red[h][t][r][l] = acc[t][r];
    #pragma unroll
    for (int r = 0; r < 4; ++r) red[h][4][r][l] = acd[r];
  }
  __syncthreads();

  if (!js) {
    #pragma unroll
    for (int t = 0; t < 4; ++t)
      #pragma unroll
      for (int r = 0; r < 4; ++r) acc[t][r] += red[h][t][r][l];
    #pragma unroll
    for (int r = 0; r < 4; ++r) acd[r] += red[h][4][r][l];

    float rl[4];
    #pragma unroll
    for (int r = 0; r < 4; ++r) rl[r] = 1.0f / acd[r];
    #pragma unroll
    for (int t = 0; t < 4; ++t) {
      #pragma unroll
      for (int r = 0; r < 4; ++r) {
        const int i = i0 + grp * 4 + r;
        const size_t oidx = ((size_t)(b * NN + i) * COLS) + h * 64 + t * 16 + r16;
        out[oidx] = acc[t][r] * rl[r];
      }
    }
  }
}

// ---------------------------------------------------------------------------
extern "C" void kernel_launch(void* const* d_in, const int* in_sizes, int n_in,
                              void* d_out, int out_size, void* d_ws, size_t ws_size,
                              hipStream_t stream) {
  const float* nf  = (const float*)d_in[0];
  const int*   adj = (const int*)d_in[1];
  const float* W   = (const float*)d_in[2];
  const float* att = (const float*)d_in[3];

  ushort* hB    = (ushort*)d_ws;                                  // 4 MB
  float*  s_src = (float*)((char*)d_ws + (size_t)16 * 64 * NN * 2);
  float*  s_dst = s_src + 16 * NN;

  hipLaunchKernelGGL(k1_prep, dim3(1024), dim3(256), 0, stream,
                     nf, W, att, hB, s_src, s_dst);
  hipLaunchKernelGGL(k2_main, dim3(512), dim3(512), 0, stream,
                     adj, hB, s_src, s_dst, (float*)d_out);
}